// Round 1
// baseline (1843.848 us; speedup 1.0000x reference)
//
#include <hip/hip_runtime.h>

#define T_LEN 512
#define F_DIM 6
#define H_DIM 64

__global__ __launch_bounds__(64, 4) void liquid_rnn_kernel(
    const float* __restrict__ x_seq,   // (B,T,F)
    const float* __restrict__ dt_p,    // scalar
    const float* __restrict__ W_in,    // (H,F)
    const float* __restrict__ b_in,    // (H)
    const float* __restrict__ W_rec,   // (H,H)
    const float* __restrict__ b_rec,   // (H)
    const float* __restrict__ tau,     // (H)
    const float* __restrict__ W_cls,   // (1,H)
    const float* __restrict__ b_cls,   // (1)
    const int*   __restrict__ ode_steps_p,
    float* __restrict__ out,           // (B,T,1)
    int B)
{
    const int b = blockIdx.x;
    if (b >= B) return;
    const int j = threadIdx.x;  // lane 0..63, owns h[j]

    const int   ode_steps = ode_steps_p[0];
    const float dtv       = dt_p[0];
    const float steps_dt  = dtv / (float)ode_steps;
    const float decay     = __expf(-steps_dt / fabsf(tau[j]));
    const float omd       = 1.0f - decay;

    // W_rec row j into registers: lane j computes h_new[j] = sum_k h[k]*W_rec[j][k]
    float wrow[H_DIM];
#pragma unroll
    for (int k = 0; k < H_DIM; ++k) wrow[k] = W_rec[j * H_DIM + k];

    float win[F_DIM];
#pragma unroll
    for (int f = 0; f < F_DIM; ++f) win[f] = W_in[j * F_DIM + f];

    const float bias_u = b_in[j] + b_rec[j];  // both appear inside tanh argument
    const float wc     = W_cls[j];
    const float bc     = b_cls[0];

    __shared__ __align__(16) float hs[H_DIM];

    float h = 0.0f;
    const float* xrow = x_seq + (size_t)b * T_LEN * F_DIM;
    float* orow = out + (size_t)b * T_LEN;

    for (int t = 0; t < T_LEN; ++t) {
        // u_t[j] = b_in[j] + b_rec[j] + sum_f x[b,t,f] * W_in[j][f]
        float u = bias_u;
#pragma unroll
        for (int f = 0; f < F_DIM; ++f) u = fmaf(xrow[t * F_DIM + f], win[f], u);

        for (int s = 0; s < ode_steps; ++s) {
            __syncthreads();          // WAR: prior reads of hs done
            hs[j] = h;
            __syncthreads();          // RAW: h visible to all lanes

            float a0 = 0.f, a1 = 0.f, a2 = 0.f, a3 = 0.f;
#pragma unroll
            for (int k = 0; k < H_DIM; k += 4) {
                float4 hk = *(const float4*)&hs[k];   // uniform addr -> LDS broadcast
                a0 = fmaf(hk.x, wrow[k + 0], a0);
                a1 = fmaf(hk.y, wrow[k + 1], a1);
                a2 = fmaf(hk.z, wrow[k + 2], a2);
                a3 = fmaf(hk.w, wrow[k + 3], a3);
            }
            float z = u + ((a0 + a1) + (a2 + a3));

            // tanh(z) = sign(z) * (1 - e) / (1 + e),  e = exp(-2|z|)  (overflow-safe)
            float az = fabsf(z);
            float e  = __expf(-2.0f * az);
            float tn = (1.0f - e) / (1.0f + e);
            tn = copysignf(tn, z);

            h = h * decay + tn * omd;
        }

        // logits[b,t] = sum_j h[j]*W_cls[j] + b_cls  (wave reduction)
        float p = h * wc;
#pragma unroll
        for (int off = 32; off; off >>= 1) p += __shfl_xor(p, off);
        if (j == 0) orow[t] = p + bc;
    }
}

extern "C" void kernel_launch(void* const* d_in, const int* in_sizes, int n_in,
                              void* d_out, int out_size, void* d_ws, size_t ws_size,
                              hipStream_t stream) {
    const float* x_seq = (const float*)d_in[0];
    const float* dt_p  = (const float*)d_in[1];
    const float* W_in  = (const float*)d_in[2];
    const float* b_in  = (const float*)d_in[3];
    const float* W_rec = (const float*)d_in[4];
    const float* b_rec = (const float*)d_in[5];
    const float* tau   = (const float*)d_in[6];
    const float* W_cls = (const float*)d_in[7];
    const float* b_cls = (const float*)d_in[8];
    const int*   ode_s = (const int*)d_in[9];
    float* outp = (float*)d_out;

    const int B = in_sizes[0] / (T_LEN * F_DIM);  // 4096

    liquid_rnn_kernel<<<B, 64, 0, stream>>>(x_seq, dt_p, W_in, b_in, W_rec, b_rec,
                                            tau, W_cls, b_cls, ode_s, outp, B);
}

// Round 2
// 1102.313 us; speedup vs baseline: 1.6727x; 1.6727x over previous
//
#include <hip/hip_runtime.h>

#define T_LEN 512
#define F_DIM 6
#define H_DIM 64

typedef _Float16 h2 __attribute__((ext_vector_type(2)));

__global__ __launch_bounds__(64, 4) void liquid_rnn_kernel(
    const float* __restrict__ x_seq,   // (B,T,F)
    const float* __restrict__ dt_p,    // scalar
    const float* __restrict__ W_in,    // (H,F)
    const float* __restrict__ b_in,    // (H)
    const float* __restrict__ W_rec,   // (H,H)
    const float* __restrict__ b_rec,   // (H)
    const float* __restrict__ tau,     // (H)
    const float* __restrict__ W_cls,   // (1,H)
    const float* __restrict__ b_cls,   // (1)
    const int*   __restrict__ ode_steps_p,
    float* __restrict__ out,           // (B,T,1)
    int B)
{
    const int b = blockIdx.x;
    if (b >= B) return;
    const int j = threadIdx.x;  // lane 0..63, owns h[j]

    const int   ode_steps = ode_steps_p[0];
    const float steps_dt  = dt_p[0] / (float)ode_steps;
    const float decay     = __expf(-steps_dt / fabsf(tau[j]));
    const float omd       = 1.0f - decay;

    // W_rec row j packed to fp16 pairs: lane j computes sum_k h[k]*W_rec[j][k]
    h2 wrow[H_DIM / 2];
#pragma unroll
    for (int k = 0; k < H_DIM / 2; ++k) {
        h2 w;
        w.x = (_Float16)W_rec[j * H_DIM + 2 * k + 0];
        w.y = (_Float16)W_rec[j * H_DIM + 2 * k + 1];
        wrow[k] = w;
    }

    float win[F_DIM];
#pragma unroll
    for (int f = 0; f < F_DIM; ++f) win[f] = W_in[j * F_DIM + f];

    const float bias_u = b_in[j] + b_rec[j];  // both inside tanh argument
    const float wc     = W_cls[j];
    const float bc     = b_cls[0];

    __shared__ __align__(16) _Float16 hsf[H_DIM];

    float h = 0.0f;
    const float* xrow = x_seq + (size_t)b * T_LEN * F_DIM;
    float* orow = out + (size_t)b * T_LEN;

    for (int t = 0; t < T_LEN; ++t) {
        // u_t[j] = b_in[j] + b_rec[j] + sum_f x[b,t,f] * W_in[j][f]   (f32)
        float u = bias_u;
#pragma unroll
        for (int f = 0; f < F_DIM; ++f) u = fmaf(xrow[t * F_DIM + f], win[f], u);

        for (int s = 0; s < ode_steps; ++s) {
            // broadcast h via LDS (single wave: lockstep, no barrier needed)
            hsf[j] = (_Float16)h;
            asm volatile("s_waitcnt lgkmcnt(0)" ::: "memory");

            float a0 = 0.f, a1 = 0.f, a2 = 0.f, a3 = 0.f;
            const uint4* hp = (const uint4*)hsf;  // 8x uint4 = 64 halves
#pragma unroll
            for (int c = 0; c < 8; ++c) {
                uint4 hv = hp[c];  // uniform addr -> LDS broadcast, conflict-free
                a0 = __builtin_amdgcn_fdot2(__builtin_bit_cast(h2, hv.x), wrow[c * 4 + 0], a0, false);
                a1 = __builtin_amdgcn_fdot2(__builtin_bit_cast(h2, hv.y), wrow[c * 4 + 1], a1, false);
                a2 = __builtin_amdgcn_fdot2(__builtin_bit_cast(h2, hv.z), wrow[c * 4 + 2], a2, false);
                a3 = __builtin_amdgcn_fdot2(__builtin_bit_cast(h2, hv.w), wrow[c * 4 + 3], a3, false);
            }
            float z = u + ((a0 + a1) + (a2 + a3));

            // tanh(z) = 1 - 2/(exp(2z)+1), overflow-safe both directions
            float e2z = __builtin_amdgcn_exp2f(z * 2.8853900817779268f);  // 2*log2(e)
            float tn  = fmaf(-2.0f, __builtin_amdgcn_rcpf(1.0f + e2z), 1.0f);

            h = fmaf(h, decay, tn * omd);
        }

        // logits[b,t] = sum_j h[j]*W_cls[j] + b_cls  (wave reduction)
        float p = h * wc;
#pragma unroll
        for (int off = 32; off; off >>= 1) p += __shfl_xor(p, off);
        if (j == 0) orow[t] = p + bc;
    }
}

extern "C" void kernel_launch(void* const* d_in, const int* in_sizes, int n_in,
                              void* d_out, int out_size, void* d_ws, size_t ws_size,
                              hipStream_t stream) {
    const float* x_seq = (const float*)d_in[0];
    const float* dt_p  = (const float*)d_in[1];
    const float* W_in  = (const float*)d_in[2];
    const float* b_in  = (const float*)d_in[3];
    const float* W_rec = (const float*)d_in[4];
    const float* b_rec = (const float*)d_in[5];
    const float* tau   = (const float*)d_in[6];
    const float* W_cls = (const float*)d_in[7];
    const float* b_cls = (const float*)d_in[8];
    const int*   ode_s = (const int*)d_in[9];
    float* outp = (float*)d_out;

    const int B = in_sizes[0] / (T_LEN * F_DIM);  // 4096

    liquid_rnn_kernel<<<B, 64, 0, stream>>>(x_seq, dt_p, W_in, b_in, W_rec, b_rec,
                                            tau, W_cls, b_cls, ode_s, outp, B);
}